// Round 12
// baseline (295.774 us; speedup 1.0000x reference)
//
#include <hip/hip_runtime.h>
#include <hip/hip_bf16.h>

typedef unsigned short u16;
typedef __attribute__((ext_vector_type(8))) short bf16x8;
typedef __attribute__((ext_vector_type(8))) unsigned short u16x8;
typedef __attribute__((ext_vector_type(4))) float f32x4;

// B=1, T=2048, DIM=2048, H=16, KV=4, HD=128
#define T_SEQ 2048
#define DIM   2048
#define NH    16
#define NKV   4
#define HD    128
#define NQKV  3072                   // fused Q|K|V output width
#define SCALE 0.08838834764831845f   // 1/sqrt(128), folded into Q at rope

__device__ __forceinline__ u16 f2bf(float f) {
  unsigned int u = __float_as_uint(f);
  unsigned int r = (u + 0x7fffu + ((u >> 16) & 1u)) >> 16;
  return (u16)r;
}
__device__ __forceinline__ float bf2f(u16 v) {
  return __uint_as_float(((unsigned int)v) << 16);
}

// ---------------- fused cast fp32 -> bf16 for all 5 inputs ----------------
// float4 ranges: x[0,B1) wq[B1,B2) wk[B2,B3) wv[B3,B4) wo[B4,B5)
#define B1 1048576
#define B2 2097152
#define B3 2359296
#define B4 2621440
#define B5 3670016
__global__ void cast_all(const float4* __restrict__ x,  const float4* __restrict__ wq,
                         const float4* __restrict__ wk, const float4* __restrict__ wv,
                         const float4* __restrict__ wo,
                         ushort4* __restrict__ xb, ushort4* __restrict__ wqkvb,
                         ushort4* __restrict__ wob) {
  int i = blockIdx.x * 256 + threadIdx.x;
  const float4* src; ushort4* dst; int j;
  if (i < B1)      { src = x;  dst = xb;               j = i; }
  else if (i < B2) { src = wq; dst = wqkvb;            j = i - B1; }
  else if (i < B3) { src = wk; dst = wqkvb + 1048576;  j = i - B2; }  // row 2048
  else if (i < B4) { src = wv; dst = wqkvb + 1310720;  j = i - B3; }  // row 2560
  else             { src = wo; dst = wob;              j = i - B4; }
  float4 v = src[j];
  ushort4 o;
  o.x = f2bf(v.x); o.y = f2bf(v.y); o.z = f2bf(v.z); o.w = f2bf(v.w);
  dst[j] = o;
}

// ---------------- GEMM: C(M,N) = A(M,K) @ W(N,K)^T, bf16 in ----------------
// r0 staging structure (padded LDS + reg-staged loads), BN=32 (r12): continue
// r8's measured-win direction — blocks x2 again (QKV-sk 12/CU, proj 4/CU).
// 4 waves each own a 32-row stripe x full 32 cols. LDS 22 KB, acc 16 VGPR.
#define BM 128
#define BN 32
#define BK 64
#define LDP 72   // padded LDS pitch (elements)

// proj gemm: full-K, fp32 or bf16 out
__global__ __launch_bounds__(256) void gemm_bt(
    const u16* __restrict__ A, const u16* __restrict__ W,
    float* __restrict__ Cf, u16* __restrict__ Cb, int M, int N, int K)
{
  __shared__ u16 As[BM * LDP];
  __shared__ u16 Bs[BN * LDP];
  const int tid  = threadIdx.x;
  const int lane = tid & 63;
  const int wave = tid >> 6;
  const int ln   = lane & 15;
  const int quad = lane >> 4;
  const int m0 = blockIdx.y * BM;
  const int n0 = blockIdx.x * BN;
  const int wm = wave * 32;          // wave's 32-row stripe

  const int sr = tid >> 3;        // 0..31
  const int sc = (tid & 7) * 8;   // 0,8,...,56

  f32x4 acc[2][2] = {};

  for (int k0 = 0; k0 < K; k0 += BK) {
#pragma unroll
    for (int c = 0; c < 4; ++c) {
      int row = c * 32 + sr;
      *(bf16x8*)&As[row * LDP + sc] =
          *(const bf16x8*)&A[(size_t)(m0 + row) * K + k0 + sc];
    }
    *(bf16x8*)&Bs[sr * LDP + sc] =
        *(const bf16x8*)&W[(size_t)(n0 + sr) * K + k0 + sc];
    __syncthreads();
#pragma unroll
    for (int ks = 0; ks < 2; ++ks) {
      bf16x8 af[2], bfr[2];
#pragma unroll
      for (int mt = 0; mt < 2; ++mt)
        af[mt] = *(const bf16x8*)&As[(wm + mt * 16 + ln) * LDP + ks * 32 + quad * 8];
#pragma unroll
      for (int nt = 0; nt < 2; ++nt)
        bfr[nt] = *(const bf16x8*)&Bs[(nt * 16 + ln) * LDP + ks * 32 + quad * 8];
#pragma unroll
      for (int mt = 0; mt < 2; ++mt)
#pragma unroll
        for (int nt = 0; nt < 2; ++nt)
          acc[mt][nt] = __builtin_amdgcn_mfma_f32_16x16x32_bf16(
              af[mt], bfr[nt], acc[mt][nt], 0, 0, 0);
    }
    __syncthreads();
  }

#pragma unroll
  for (int mt = 0; mt < 2; ++mt)
#pragma unroll
    for (int nt = 0; nt < 2; ++nt)
#pragma unroll
      for (int r = 0; r < 4; ++r) {
        int row = m0 + wm + mt * 16 + quad * 4 + r;
        int col = n0 + nt * 16 + ln;
        if (Cb) Cb[(size_t)row * N + col] = f2bf(acc[mt][nt][r]);
        else    Cf[(size_t)row * N + col] = acc[mt][nt][r];
      }
}

// QKV gemm, split-K: blockIdx.z = chunk (2 x K/2). Partial C (bf16) per
// chunk; the chunk-sum is folded into rope_fused (which consumes every
// element of QKV exactly once). 3072 blocks = 12/CU, 8 iters/block.
__global__ __launch_bounds__(256) void gemm_qkv_sk(
    const u16* __restrict__ A, const u16* __restrict__ W,
    u16* __restrict__ Cp, int M, int N, int K)
{
  __shared__ u16 As[BM * LDP];
  __shared__ u16 Bs[BN * LDP];
  const int tid  = threadIdx.x;
  const int lane = tid & 63;
  const int wave = tid >> 6;
  const int ln   = lane & 15;
  const int quad = lane >> 4;
  const int m0 = blockIdx.y * BM;
  const int n0 = blockIdx.x * BN;
  const int wm = wave * 32;
  const int kBeg = blockIdx.z * (K >> 1);
  const int kEnd = kBeg + (K >> 1);
  u16* C = Cp + (size_t)blockIdx.z * M * N;

  const int sr = tid >> 3;
  const int sc = (tid & 7) * 8;

  f32x4 acc[2][2] = {};

  for (int k0 = kBeg; k0 < kEnd; k0 += BK) {
#pragma unroll
    for (int c = 0; c < 4; ++c) {
      int row = c * 32 + sr;
      *(bf16x8*)&As[row * LDP + sc] =
          *(const bf16x8*)&A[(size_t)(m0 + row) * K + k0 + sc];
    }
    *(bf16x8*)&Bs[sr * LDP + sc] =
        *(const bf16x8*)&W[(size_t)(n0 + sr) * K + k0 + sc];
    __syncthreads();
#pragma unroll
    for (int ks = 0; ks < 2; ++ks) {
      bf16x8 af[2], bfr[2];
#pragma unroll
      for (int mt = 0; mt < 2; ++mt)
        af[mt] = *(const bf16x8*)&As[(wm + mt * 16 + ln) * LDP + ks * 32 + quad * 8];
#pragma unroll
      for (int nt = 0; nt < 2; ++nt)
        bfr[nt] = *(const bf16x8*)&Bs[(nt * 16 + ln) * LDP + ks * 32 + quad * 8];
#pragma unroll
      for (int mt = 0; mt < 2; ++mt)
#pragma unroll
        for (int nt = 0; nt < 2; ++nt)
          acc[mt][nt] = __builtin_amdgcn_mfma_f32_16x16x32_bf16(
              af[mt], bfr[nt], acc[mt][nt], 0, 0, 0);
    }
    __syncthreads();
  }

#pragma unroll
  for (int mt = 0; mt < 2; ++mt)
#pragma unroll
    for (int nt = 0; nt < 2; ++nt)
#pragma unroll
      for (int r = 0; r < 4; ++r) {
        int row = m0 + wm + mt * 16 + quad * 4 + r;
        int col = n0 + nt * 16 + ln;
        C[(size_t)row * N + col] = f2bf(acc[mt][nt][r]);
      }
}

// ---------------- fused RoPE-Q (scaled) + RoPE-K + V-transpose -------------
// Consumes the two split-K partials (P0+P1 summed in fp32) — the free
// chunk-reduce. Vectorized ushort8 (G13). K output [g][t][d]; V [g][d][t].
// grid: Q 2048 blocks | K 512 | V 256  = 2816 blocks x 256 threads.
__global__ __launch_bounds__(256) void rope_fused(
    const u16* __restrict__ P0, const u16* __restrict__ P1,
    const float* __restrict__ cosT, const float* __restrict__ sinT,
    u16* __restrict__ Qs, u16* __restrict__ Kb, u16* __restrict__ Vt)
{
  const int blk = blockIdx.x, tid = threadIdx.x;
  if (blk < 2048) {                           // ---- RoPE Q (+SCALE) ----
    int e = blk * 2048 + tid * 8;
    int t = e >> 11, rem = e & 2047;
    int h = rem >> 7, d0 = rem & 127;
    size_t off = (size_t)t * NQKV + h * HD;
    u16x8 va = *(const u16x8*)&P0[off + d0];
    u16x8 vb = *(const u16x8*)&P1[off + d0];
    u16x8 pa = *(const u16x8*)&P0[off + (d0 ^ 64)];
    u16x8 pb = *(const u16x8*)&P1[off + (d0 ^ 64)];
    float4 c0 = *(const float4*)&cosT[t * HD + d0];
    float4 c1 = *(const float4*)&cosT[t * HD + d0 + 4];
    float4 s0 = *(const float4*)&sinT[t * HD + d0];
    float4 s1 = *(const float4*)&sinT[t * HD + d0 + 4];
    float cc[8] = {c0.x, c0.y, c0.z, c0.w, c1.x, c1.y, c1.z, c1.w};
    float ss[8] = {s0.x, s0.y, s0.z, s0.w, s1.x, s1.y, s1.z, s1.w};
    float sgn = (d0 < 64) ? -1.f : 1.f;
    u16x8 o;
#pragma unroll
    for (int j = 0; j < 8; ++j) {
      float u = bf2f(va[j]) + bf2f(vb[j]);
      float pr = bf2f(pa[j]) + bf2f(pb[j]);
      o[j] = f2bf((u * cc[j] + sgn * pr * ss[j]) * SCALE);
    }
    *(u16x8*)&Qs[(size_t)(t * NH + h) * HD + d0] = o;
  } else if (blk < 2560) {                    // ---- RoPE K -> [g][t][d] ----
    int e = (blk - 2048) * 2048 + tid * 8;
    int t = e >> 9, rem = e & 511;
    int g = rem >> 7, d0 = rem & 127;
    size_t off = (size_t)t * NQKV + DIM + g * HD;
    u16x8 va = *(const u16x8*)&P0[off + d0];
    u16x8 vb = *(const u16x8*)&P1[off + d0];
    u16x8 pa = *(const u16x8*)&P0[off + (d0 ^ 64)];
    u16x8 pb = *(const u16x8*)&P1[off + (d0 ^ 64)];
    float4 c0 = *(const float4*)&cosT[t * HD + d0];
    float4 c1 = *(const float4*)&cosT[t * HD + d0 + 4];
    float4 s0 = *(const float4*)&sinT[t * HD + d0];
    float4 s1 = *(const float4*)&sinT[t * HD + d0 + 4];
    float cc[8] = {c0.x, c0.y, c0.z, c0.w, c1.x, c1.y, c1.z, c1.w};
    float ss[8] = {s0.x, s0.y, s0.z, s0.w, s1.x, s1.y, s1.z, s1.w};
    float sgn = (d0 < 64) ? -1.f : 1.f;
    u16x8 o;
#pragma unroll
    for (int j = 0; j < 8; ++j) {
      float u = bf2f(va[j]) + bf2f(vb[j]);
      float pr = bf2f(pa[j]) + bf2f(pb[j]);
      o[j] = f2bf(u * cc[j] + sgn * pr * ss[j]);
    }
    *(u16x8*)&Kb[((size_t)g * T_SEQ + t) * HD + d0] = o;
  } else {                                    // ---- V transpose 64x64 tile ----
    __shared__ u16 Vls[64][72];
    int bv = blk - 2560;                      // 0..255
    int g  = bv >> 6, rem = bv & 63;
    int dt = rem >> 5, tt = rem & 31;
    int t0 = tt * 64, db = dt * 64;
    {
      int lr = tid >> 2, lc = (tid & 3) * 16;
      size_t off = (size_t)(t0 + lr) * NQKV + DIM + NKV * HD + g * HD + db + lc;
      u16x8 a0 = *(const u16x8*)&P0[off],     b0 = *(const u16x8*)&P1[off];
      u16x8 a1 = *(const u16x8*)&P0[off + 8], b1 = *(const u16x8*)&P1[off + 8];
      u16x8 w0, w1;
#pragma unroll
      for (int j = 0; j < 8; ++j) {
        w0[j] = f2bf(bf2f(a0[j]) + bf2f(b0[j]));
        w1[j] = f2bf(bf2f(a1[j]) + bf2f(b1[j]));
      }
      *(u16x8*)&Vls[lr][lc]     = w0;
      *(u16x8*)&Vls[lr][lc + 8] = w1;
    }
    __syncthreads();
    {
      int dr = tid >> 2, tc = (tid & 3) * 16;
      u16x8 a, b;
#pragma unroll
      for (int j = 0; j < 8; ++j) {
        a[j] = Vls[tc + j][dr];
        b[j] = Vls[tc + 8 + j][dr];
      }
      u16* dst = Vt + (size_t)(g * HD + db + dr) * T_SEQ + t0 + tc;
      *(u16x8*)&dst[0] = a;
      *(u16x8*)&dst[8] = b;
    }
  }
}

// ---------------- Flash pass 1: split-K partials ---------------------------
// r5 proven compute body + r11 balanced chunks + LPT dispatch (53.6 us).
// grid (16 h, 40 pairs), block 256 = 4 waves x 32 q-rows.
// Opart: per (h,qi,c) slot, 128x128 bf16. lpart: 128 fp32 per slot.
// slot = h*40 + 2*b*(b+1) + (qi&3)*(b+1) + c, b = qi>>2 (=nchunks-1).
#define KSP 136
#define VSP 72
#define PSP 72
__device__ const signed char qiT[40] = {
  15,15,15,15,11,11,11,14,14,10, 7, 7, 3,      // 8-iter blocks
  14,14,13,13,13,13,12,12,10,10, 9, 9, 6, 6,   // 7-iter
  12,12, 9, 8, 8, 8, 5, 5, 2,                  // 6-iter
   4, 4, 1, 0};                                 // 5,5,4,2
__device__ const signed char cT[40] = {
   0, 1, 2, 3, 0, 1, 2, 1, 3, 2, 0, 1, 0,
   0, 2, 0, 1, 2, 3, 1, 3, 0, 1, 1, 2, 0, 1,
   0, 2, 0, 0, 1, 2, 0, 1, 0,
   0, 1, 0, 0};
__global__ __launch_bounds__(256) void flash_partial(
    const u16* __restrict__ Qs, const u16* __restrict__ Kb,
    const u16* __restrict__ Vt, u16* __restrict__ Opart,
    float* __restrict__ lpart)
{
  const int h    = blockIdx.x;
  const int pidx = blockIdx.y;
  const int qi = qiT[pidx];
  const int c  = cT[pidx];
  const int b  = qi >> 2;            // nchunks-1
  const int g  = h >> 2;
  const int q0 = qi << 7;
  const int nt = 2 * (qi + 1);       // key-tiles for this q-tile
  const int nc = b + 1;
  const int k0   = ((c * nt) / nc) << 6;
  const int kend = (((c + 1) * nt) / nc) << 6;

  __shared__ u16 Ks[64 * KSP];       // 17408 B
  __shared__ u16 Vs[HD * VSP];       // 18432 B
  __shared__ u16 Ps[4][32 * PSP];    // 18432 B: per-wave 32-row P (both m-tiles)

  const int tid  = threadIdx.x;
  const int lane = tid & 63;
  const int w    = tid >> 6;
  const int ln   = lane & 15;
  const int quad = lane >> 4;

  // Q A-fragments for this wave's two 16-row m-tiles
  bf16x8 aq[2][4];
#pragma unroll
  for (int mt = 0; mt < 2; ++mt) {
    const u16* qp = Qs + ((size_t)(q0 + w * 32 + mt * 16 + ln) * NH + h) * HD + quad * 8;
#pragma unroll
    for (int ks = 0; ks < 4; ++ks) aq[mt][ks] = *(const bf16x8*)&qp[ks * 32];
  }

  f32x4 o[2][8] = {};
  float rs[2][4] = {};

  const int rb0 = q0 + w * 32 + quad * 4;        // mt=0 row base (this lane)
  const int rb1 = rb0 + 16;                      // mt=1 row base
  const int rmax0 = q0 + w * 32 + 15;            // last row of m-tile 0
  const int rmax1 = q0 + w * 32 + 31;            // last row of m-tile 1

  const u16* kbase = Kb + (size_t)g * T_SEQ * HD;     // [t][d], row stride HD

  for (int jb = k0; jb < kend; jb += 64) {
    // stage K tile (64 keys x 128 d) — contiguous 16 KB stream
    {
      int r = tid >> 4, cc = (tid & 15) * 8;
#pragma unroll
      for (int i = 0; i < 4; ++i) {
        int row = i * 16 + r;
        *(bf16x8*)&Ks[row * KSP + cc] =
            *(const bf16x8*)&kbase[(size_t)(jb + row) * HD + cc];
      }
    }
    // stage V^T tile (128 d x 64 keys)
    {
      int r = tid >> 3, cc = (tid & 7) * 8;
#pragma unroll
      for (int i = 0; i < 4; ++i) {
        int row = i * 32 + r;
        *(bf16x8*)&Vs[row * VSP + cc] =
            *(const bf16x8*)&Vt[(size_t)(g * HD + row) * T_SEQ + jb + cc];
      }
    }
    __syncthreads();

    if (jb <= rmax1) {                 // wave has live rows for this tile
      const bool do0  = (jb <= rmax0);
      const bool diag = (jb >= q0);

      // ---- QK^T: each kf fragment read once, feeds both m-tiles ----
#pragma unroll
      for (int nb = 0; nb < 4; ++nb) {
        bf16x8 kf[4];
#pragma unroll
        for (int ks = 0; ks < 4; ++ks)
          kf[ks] = *(const bf16x8*)&Ks[(nb * 16 + ln) * KSP + ks * 32 + quad * 8];
        f32x4 s0 = {}, s1 = {};
#pragma unroll
        for (int ks = 0; ks < 4; ++ks) {
          if (do0) s0 = __builtin_amdgcn_mfma_f32_16x16x32_bf16(aq[0][ks], kf[ks], s0, 0, 0, 0);
          s1 = __builtin_amdgcn_mfma_f32_16x16x32_bf16(aq[1][ks], kf[ks], s1, 0, 0, 0);
        }
        const int j = jb + nb * 16 + ln;
#pragma unroll
        for (int r = 0; r < 4; ++r) {
          if (do0) {
            float p = (!diag || j <= rb0 + r) ? __expf(s0[r]) : 0.f;
            rs[0][r] += p;
            Ps[w][(quad * 4 + r) * PSP + nb * 16 + ln] = f2bf(p);
          }
          float p1 = (!diag || j <= rb1 + r) ? __expf(s1[r]) : 0.f;
          rs[1][r] += p1;
          Ps[w][(16 + quad * 4 + r) * PSP + nb * 16 + ln] = f2bf(p1);
        }
      }

      // ---- PV: each bv fragment read once, feeds both m-tiles ----
#pragma unroll
      for (int kst = 0; kst < 2; ++kst) {
        bf16x8 ap0, ap1;
        if (do0) ap0 = *(const bf16x8*)&Ps[w][ln * PSP + kst * 32 + quad * 8];
        ap1 = *(const bf16x8*)&Ps[w][(16 + ln) * PSP + kst * 32 + quad * 8];
#pragma unroll
        for (int nb8 = 0; nb8 < 8; ++nb8) {
          bf16x8 bv = *(const bf16x8*)&Vs[(nb8 * 16 + ln) * VSP + kst * 32 + quad * 8];
          if (do0) o[0][nb8] = __builtin_amdgcn_mfma_f32_16x16x32_bf16(ap0, bv, o[0][nb8], 0, 0, 0);
          o[1][nb8] = __builtin_amdgcn_mfma_f32_16x16x32_bf16(ap1, bv, o[1][nb8], 0, 0, 0);
        }
      }
    }
    __syncthreads();
  }

  // epilogue: write O partial (bf16) + row-sum partial (fp32)
  const int slot = h * 40 + 2 * b * (b + 1) + (qi & 3) * (b + 1) + c;
  u16*   op = Opart + (size_t)slot * (128 * 128);
  float* lp = lpart + (size_t)slot * 128;
#pragma unroll
  for (int mt = 0; mt < 2; ++mt) {
#pragma unroll
    for (int r = 0; r < 4; ++r)
#pragma unroll
      for (int off = 1; off < 16; off <<= 1)
        rs[mt][r] += __shfl_xor(rs[mt][r], off);
    int rowb = w * 32 + mt * 16 + quad * 4;
#pragma unroll
    for (int r = 0; r < 4; ++r) {
#pragma unroll
      for (int nb8 = 0; nb8 < 8; ++nb8)
        op[(rowb + r) * 128 + nb8 * 16 + ln] = f2bf(o[mt][nb8][r]);
      if (ln == 0) lp[rowb + r] = rs[mt][r];
    }
  }
}

// ---------------- Flash pass 2: reduce chunks + normalize ------------------
// Vectorized (G13): ushort8 per chunk per thread. block 256 = 16 t-rows x
// (16 threads x 8 d).  grid (T/16, NH).
__global__ __launch_bounds__(256) void flash_reduce(
    const u16* __restrict__ Opart, const float* __restrict__ lpart,
    u16* __restrict__ AO)
{
  const int h = blockIdx.y;
  const int tid = threadIdx.x;
  const int dgrp = tid & 15, trow = tid >> 4;
  const int t = blockIdx.x * 16 + trow;
  const int d0 = dgrp * 8;
  const int qi = t >> 7, r = t & 127;
  const int b = qi >> 2;
  const int base = h * 40 + 2 * b * (b + 1) + (qi & 3) * (b + 1);
  float so[8] = {};
  float sl = 0.f;
  for (int cc = 0; cc <= b; ++cc) {
    u16x8 ov = *(const u16x8*)&Opart[(size_t)(base + cc) * (128 * 128) + r * 128 + d0];
#pragma unroll
    for (int j = 0; j < 8; ++j) so[j] += bf2f(ov[j]);
    sl += lpart[(size_t)(base + cc) * 128 + r];
  }
  const float inv = 1.f / sl;
  u16x8 o;
#pragma unroll
  for (int j = 0; j < 8; ++j) o[j] = f2bf(so[j] * inv);
  *(u16x8*)&AO[(size_t)t * DIM + h * HD + d0] = o;
}

// ---------------- launch ----------------
// Workspace (peak 52 MB, proven safe):
//   [ 0,  8) xb bf16          (dead after QKV gemm) -> AO overlays
//   [ 8, 20) wqkvb bf16       (dead after QKV gemm) -> Qs@8, Kb@16, Vt@18
//   [20, 28) wob bf16         (live till final gemm)
//   [28, 40) P0 bf16 (QKV split-K chunk 0; dead after rope) -> Opart [28,48)
//   [40, 52) P1 bf16 (chunk 1; dead after rope)
//   [48, 48.4) lpart fp32     (written in flash, after P1 dead)
extern "C" void kernel_launch(void* const* d_in, const int* in_sizes, int n_in,
                              void* d_out, int out_size, void* d_ws, size_t ws_size,
                              hipStream_t stream) {
  const float* x    = (const float*)d_in[0];
  const float* wq   = (const float*)d_in[1];
  const float* wk   = (const float*)d_in[2];
  const float* wv   = (const float*)d_in[3];
  const float* wo   = (const float*)d_in[4];
  const float* cosT = (const float*)d_in[5];
  const float* sinT = (const float*)d_in[6];
  float* out = (float*)d_out;

  char* ws = (char*)d_ws;
  const size_t MB = 1024 * 1024;
  u16*   xb    = (u16*)(ws + 0 * MB);
  u16*   wqkvb = (u16*)(ws + 8 * MB);
  u16*   wob   = (u16*)(ws + 20 * MB);
  u16*   P0    = (u16*)(ws + 28 * MB);   // QKV split-K partials
  u16*   P1    = (u16*)(ws + 40 * MB);
  u16*   Qs    = (u16*)(ws + 8 * MB);    // overlays wqkvb (dead)
  u16*   Kb    = (u16*)(ws + 16 * MB);
  u16*   Vt    = (u16*)(ws + 18 * MB);
  u16*   AO    = (u16*)(ws + 0 * MB);    // overlays xb (dead)
  u16*   Opart = (u16*)(ws + 28 * MB);   // overlays P0/P1 (dead), 20 MB
  float* lpart = (float*)(ws + 48 * MB); // 320 KB

  // 1. all casts in one launch
  cast_all<<<B5 / 256, 256, 0, stream>>>(
      (const float4*)x, (const float4*)wq, (const float4*)wk, (const float4*)wv,
      (const float4*)wo, (ushort4*)xb, (ushort4*)wqkvb, (ushort4*)wob);

  // 2. fused QKV projection, split-K x2: partials P0/P1 (bf16)
  gemm_qkv_sk<<<dim3(NQKV / BN, T_SEQ / BM, 2), 256, 0, stream>>>(
      xb, wqkvb, P0, T_SEQ, NQKV, DIM);

  // 3. fused chunk-reduce + RoPE-Q(+scale) / RoPE-K([g][t][d]) / V-transpose
  rope_fused<<<2816, 256, 0, stream>>>(P0, P1, cosT, sinT, Qs, Kb, Vt);

  // 4a. flash attention pass 1 (balanced chunks, LPT dispatch order)
  flash_partial<<<dim3(NH, 40), 256, 0, stream>>>(Qs, Kb, Vt, Opart, lpart);
  // 4b. reduce + normalize (vectorized)
  flash_reduce<<<dim3(T_SEQ / 16, NH), 256, 0, stream>>>(Opart, lpart, AO);

  // 5. output projection, fp32 out
  gemm_bt<<<dim3(DIM / BN, T_SEQ / BM), 256, 0, stream>>>(
      AO, wob, out, nullptr, T_SEQ, DIM, DIM);
}

// Round 13
// 240.977 us; speedup vs baseline: 1.2274x; 1.2274x over previous
//
#include <hip/hip_runtime.h>
#include <hip/hip_bf16.h>

typedef unsigned short u16;
typedef __attribute__((ext_vector_type(8))) short bf16x8;
typedef __attribute__((ext_vector_type(8))) unsigned short u16x8;
typedef __attribute__((ext_vector_type(4))) float f32x4;

// B=1, T=2048, DIM=2048, H=16, KV=4, HD=128
#define T_SEQ 2048
#define DIM   2048
#define NH    16
#define NKV   4
#define HD    128
#define NQKV  3072                   // fused Q|K|V output width
#define SCALE 0.08838834764831845f   // 1/sqrt(128), folded into Q at rope

__device__ __forceinline__ u16 f2bf(float f) {
  unsigned int u = __float_as_uint(f);
  unsigned int r = (u + 0x7fffu + ((u >> 16) & 1u)) >> 16;
  return (u16)r;
}
__device__ __forceinline__ float bf2f(u16 v) {
  return __uint_as_float(((unsigned int)v) << 16);
}

// ---------------- fused cast fp32 -> bf16 for all 5 inputs ----------------
// float4 ranges: x[0,B1) wq[B1,B2) wk[B2,B3) wv[B3,B4) wo[B4,B5)
#define B1 1048576
#define B2 2097152
#define B3 2359296
#define B4 2621440
#define B5 3670016
__global__ void cast_all(const float4* __restrict__ x,  const float4* __restrict__ wq,
                         const float4* __restrict__ wk, const float4* __restrict__ wv,
                         const float4* __restrict__ wo,
                         ushort4* __restrict__ xb, ushort4* __restrict__ wqkvb,
                         ushort4* __restrict__ wob) {
  int i = blockIdx.x * 256 + threadIdx.x;
  const float4* src; ushort4* dst; int j;
  if (i < B1)      { src = x;  dst = xb;               j = i; }
  else if (i < B2) { src = wq; dst = wqkvb;            j = i - B1; }
  else if (i < B3) { src = wk; dst = wqkvb + 1048576;  j = i - B2; }  // row 2048
  else if (i < B4) { src = wv; dst = wqkvb + 1310720;  j = i - B3; }  // row 2560
  else             { src = wo; dst = wob;              j = i - B4; }
  float4 v = src[j];
  ushort4 o;
  o.x = f2bf(v.x); o.y = f2bf(v.y); o.z = f2bf(v.z); o.w = f2bf(v.w);
  dst[j] = o;
}

// ---------------- GEMM: C(M,N) = A(M,K) @ W(N,K)^T, bf16 in ----------------
// r0 staging structure (padded LDS + reg-staged loads) with BN=64 — the
// measured optimum of this family: BN=128 (r7) loses to 64 (r8, +11us);
// BN=32 (r12) regresses hard (overhead+overfetch regime: 58% occupancy but
// 13.8% MfmaUtil, FETCH 2.1x ideal). 4 waves each own 32 rows x 64 cols.
#define BM 128
#define BN 64
#define BK 64
#define LDP 72   // padded LDS pitch (elements)

// proj gemm: full-K, fp32 or bf16 out
__global__ __launch_bounds__(256) void gemm_bt(
    const u16* __restrict__ A, const u16* __restrict__ W,
    float* __restrict__ Cf, u16* __restrict__ Cb, int M, int N, int K)
{
  __shared__ u16 As[BM * LDP];
  __shared__ u16 Bs[BN * LDP];
  const int tid  = threadIdx.x;
  const int lane = tid & 63;
  const int wave = tid >> 6;
  const int ln   = lane & 15;
  const int quad = lane >> 4;
  const int m0 = blockIdx.y * BM;
  const int n0 = blockIdx.x * BN;
  const int wm = wave * 32;          // wave's 32-row stripe

  const int sr = tid >> 3;        // 0..31
  const int sc = (tid & 7) * 8;   // 0,8,...,56

  f32x4 acc[2][4] = {};

  for (int k0 = 0; k0 < K; k0 += BK) {
#pragma unroll
    for (int c = 0; c < 4; ++c) {
      int row = c * 32 + sr;
      *(bf16x8*)&As[row * LDP + sc] =
          *(const bf16x8*)&A[(size_t)(m0 + row) * K + k0 + sc];
    }
#pragma unroll
    for (int c = 0; c < 2; ++c) {
      int row = c * 32 + sr;
      *(bf16x8*)&Bs[row * LDP + sc] =
          *(const bf16x8*)&W[(size_t)(n0 + row) * K + k0 + sc];
    }
    __syncthreads();
#pragma unroll
    for (int ks = 0; ks < 2; ++ks) {
      bf16x8 af[2], bfr[4];
#pragma unroll
      for (int mt = 0; mt < 2; ++mt)
        af[mt] = *(const bf16x8*)&As[(wm + mt * 16 + ln) * LDP + ks * 32 + quad * 8];
#pragma unroll
      for (int nt = 0; nt < 4; ++nt)
        bfr[nt] = *(const bf16x8*)&Bs[(nt * 16 + ln) * LDP + ks * 32 + quad * 8];
#pragma unroll
      for (int mt = 0; mt < 2; ++mt)
#pragma unroll
        for (int nt = 0; nt < 4; ++nt)
          acc[mt][nt] = __builtin_amdgcn_mfma_f32_16x16x32_bf16(
              af[mt], bfr[nt], acc[mt][nt], 0, 0, 0);
    }
    __syncthreads();
  }

#pragma unroll
  for (int mt = 0; mt < 2; ++mt)
#pragma unroll
    for (int nt = 0; nt < 4; ++nt)
#pragma unroll
      for (int r = 0; r < 4; ++r) {
        int row = m0 + wm + mt * 16 + quad * 4 + r;
        int col = n0 + nt * 16 + ln;
        if (Cb) Cb[(size_t)row * N + col] = f2bf(acc[mt][nt][r]);
        else    Cf[(size_t)row * N + col] = acc[mt][nt][r];
      }
}

// QKV gemm, split-K: blockIdx.z = chunk (2 x K/2). Partial C (bf16) per
// chunk; the chunk-sum is folded into rope_fused (which consumes every
// element of QKV exactly once). 1536 blocks = 6/CU, 16 iters/block.
__global__ __launch_bounds__(256) void gemm_qkv_sk(
    const u16* __restrict__ A, const u16* __restrict__ W,
    u16* __restrict__ Cp, int M, int N, int K)
{
  __shared__ u16 As[BM * LDP];
  __shared__ u16 Bs[BN * LDP];
  const int tid  = threadIdx.x;
  const int lane = tid & 63;
  const int wave = tid >> 6;
  const int ln   = lane & 15;
  const int quad = lane >> 4;
  const int m0 = blockIdx.y * BM;
  const int n0 = blockIdx.x * BN;
  const int wm = wave * 32;
  const int kBeg = blockIdx.z * (K >> 1);
  const int kEnd = kBeg + (K >> 1);
  u16* C = Cp + (size_t)blockIdx.z * M * N;

  const int sr = tid >> 3;
  const int sc = (tid & 7) * 8;

  f32x4 acc[2][4] = {};

  for (int k0 = kBeg; k0 < kEnd; k0 += BK) {
#pragma unroll
    for (int c = 0; c < 4; ++c) {
      int row = c * 32 + sr;
      *(bf16x8*)&As[row * LDP + sc] =
          *(const bf16x8*)&A[(size_t)(m0 + row) * K + k0 + sc];
    }
#pragma unroll
    for (int c = 0; c < 2; ++c) {
      int row = c * 32 + sr;
      *(bf16x8*)&Bs[row * LDP + sc] =
          *(const bf16x8*)&W[(size_t)(n0 + row) * K + k0 + sc];
    }
    __syncthreads();
#pragma unroll
    for (int ks = 0; ks < 2; ++ks) {
      bf16x8 af[2], bfr[4];
#pragma unroll
      for (int mt = 0; mt < 2; ++mt)
        af[mt] = *(const bf16x8*)&As[(wm + mt * 16 + ln) * LDP + ks * 32 + quad * 8];
#pragma unroll
      for (int nt = 0; nt < 4; ++nt)
        bfr[nt] = *(const bf16x8*)&Bs[(nt * 16 + ln) * LDP + ks * 32 + quad * 8];
#pragma unroll
      for (int mt = 0; mt < 2; ++mt)
#pragma unroll
        for (int nt = 0; nt < 4; ++nt)
          acc[mt][nt] = __builtin_amdgcn_mfma_f32_16x16x32_bf16(
              af[mt], bfr[nt], acc[mt][nt], 0, 0, 0);
    }
    __syncthreads();
  }

#pragma unroll
  for (int mt = 0; mt < 2; ++mt)
#pragma unroll
    for (int nt = 0; nt < 4; ++nt)
#pragma unroll
      for (int r = 0; r < 4; ++r) {
        int row = m0 + wm + mt * 16 + quad * 4 + r;
        int col = n0 + nt * 16 + ln;
        C[(size_t)row * N + col] = f2bf(acc[mt][nt][r]);
      }
}

// ---------------- fused RoPE-Q (scaled) + RoPE-K + V-transpose -------------
// Consumes the two split-K partials (P0+P1 summed in fp32) — the free
// chunk-reduce. Vectorized ushort8 (G13). K output [g][t][d]; V [g][d][t].
// grid: Q 2048 blocks | K 512 | V 256  = 2816 blocks x 256 threads.
__global__ __launch_bounds__(256) void rope_fused(
    const u16* __restrict__ P0, const u16* __restrict__ P1,
    const float* __restrict__ cosT, const float* __restrict__ sinT,
    u16* __restrict__ Qs, u16* __restrict__ Kb, u16* __restrict__ Vt)
{
  const int blk = blockIdx.x, tid = threadIdx.x;
  if (blk < 2048) {                           // ---- RoPE Q (+SCALE) ----
    int e = blk * 2048 + tid * 8;
    int t = e >> 11, rem = e & 2047;
    int h = rem >> 7, d0 = rem & 127;
    size_t off = (size_t)t * NQKV + h * HD;
    u16x8 va = *(const u16x8*)&P0[off + d0];
    u16x8 vb = *(const u16x8*)&P1[off + d0];
    u16x8 pa = *(const u16x8*)&P0[off + (d0 ^ 64)];
    u16x8 pb = *(const u16x8*)&P1[off + (d0 ^ 64)];
    float4 c0 = *(const float4*)&cosT[t * HD + d0];
    float4 c1 = *(const float4*)&cosT[t * HD + d0 + 4];
    float4 s0 = *(const float4*)&sinT[t * HD + d0];
    float4 s1 = *(const float4*)&sinT[t * HD + d0 + 4];
    float cc[8] = {c0.x, c0.y, c0.z, c0.w, c1.x, c1.y, c1.z, c1.w};
    float ss[8] = {s0.x, s0.y, s0.z, s0.w, s1.x, s1.y, s1.z, s1.w};
    float sgn = (d0 < 64) ? -1.f : 1.f;
    u16x8 o;
#pragma unroll
    for (int j = 0; j < 8; ++j) {
      float u = bf2f(va[j]) + bf2f(vb[j]);
      float pr = bf2f(pa[j]) + bf2f(pb[j]);
      o[j] = f2bf((u * cc[j] + sgn * pr * ss[j]) * SCALE);
    }
    *(u16x8*)&Qs[(size_t)(t * NH + h) * HD + d0] = o;
  } else if (blk < 2560) {                    // ---- RoPE K -> [g][t][d] ----
    int e = (blk - 2048) * 2048 + tid * 8;
    int t = e >> 9, rem = e & 511;
    int g = rem >> 7, d0 = rem & 127;
    size_t off = (size_t)t * NQKV + DIM + g * HD;
    u16x8 va = *(const u16x8*)&P0[off + d0];
    u16x8 vb = *(const u16x8*)&P1[off + d0];
    u16x8 pa = *(const u16x8*)&P0[off + (d0 ^ 64)];
    u16x8 pb = *(const u16x8*)&P1[off + (d0 ^ 64)];
    float4 c0 = *(const float4*)&cosT[t * HD + d0];
    float4 c1 = *(const float4*)&cosT[t * HD + d0 + 4];
    float4 s0 = *(const float4*)&sinT[t * HD + d0];
    float4 s1 = *(const float4*)&sinT[t * HD + d0 + 4];
    float cc[8] = {c0.x, c0.y, c0.z, c0.w, c1.x, c1.y, c1.z, c1.w};
    float ss[8] = {s0.x, s0.y, s0.z, s0.w, s1.x, s1.y, s1.z, s1.w};
    float sgn = (d0 < 64) ? -1.f : 1.f;
    u16x8 o;
#pragma unroll
    for (int j = 0; j < 8; ++j) {
      float u = bf2f(va[j]) + bf2f(vb[j]);
      float pr = bf2f(pa[j]) + bf2f(pb[j]);
      o[j] = f2bf(u * cc[j] + sgn * pr * ss[j]);
    }
    *(u16x8*)&Kb[((size_t)g * T_SEQ + t) * HD + d0] = o;
  } else {                                    // ---- V transpose 64x64 tile ----
    __shared__ u16 Vls[64][72];
    int bv = blk - 2560;                      // 0..255
    int g  = bv >> 6, rem = bv & 63;
    int dt = rem >> 5, tt = rem & 31;
    int t0 = tt * 64, db = dt * 64;
    {
      int lr = tid >> 2, lc = (tid & 3) * 16;
      size_t off = (size_t)(t0 + lr) * NQKV + DIM + NKV * HD + g * HD + db + lc;
      u16x8 a0 = *(const u16x8*)&P0[off],     b0 = *(const u16x8*)&P1[off];
      u16x8 a1 = *(const u16x8*)&P0[off + 8], b1 = *(const u16x8*)&P1[off + 8];
      u16x8 w0, w1;
#pragma unroll
      for (int j = 0; j < 8; ++j) {
        w0[j] = f2bf(bf2f(a0[j]) + bf2f(b0[j]));
        w1[j] = f2bf(bf2f(a1[j]) + bf2f(b1[j]));
      }
      *(u16x8*)&Vls[lr][lc]     = w0;
      *(u16x8*)&Vls[lr][lc + 8] = w1;
    }
    __syncthreads();
    {
      int dr = tid >> 2, tc = (tid & 3) * 16;
      u16x8 a, b;
#pragma unroll
      for (int j = 0; j < 8; ++j) {
        a[j] = Vls[tc + j][dr];
        b[j] = Vls[tc + 8 + j][dr];
      }
      u16* dst = Vt + (size_t)(g * HD + db + dr) * T_SEQ + t0 + tc;
      *(u16x8*)&dst[0] = a;
      *(u16x8*)&dst[8] = b;
    }
  }
}

// ---------------- Flash pass 1: split-K partials ---------------------------
// r5 proven compute body + r11 balanced chunks + LPT dispatch (53.6 us).
// grid (16 h, 40 pairs), block 256 = 4 waves x 32 q-rows.
// Opart: per (h,qi,c) slot, 128x128 bf16. lpart: 128 fp32 per slot.
// slot = h*40 + 2*b*(b+1) + (qi&3)*(b+1) + c, b = qi>>2 (=nchunks-1).
#define KSP 136
#define VSP 72
#define PSP 72
__device__ const signed char qiT[40] = {
  15,15,15,15,11,11,11,14,14,10, 7, 7, 3,      // 8-iter blocks
  14,14,13,13,13,13,12,12,10,10, 9, 9, 6, 6,   // 7-iter
  12,12, 9, 8, 8, 8, 5, 5, 2,                  // 6-iter
   4, 4, 1, 0};                                 // 5,5,4,2
__device__ const signed char cT[40] = {
   0, 1, 2, 3, 0, 1, 2, 1, 3, 2, 0, 1, 0,
   0, 2, 0, 1, 2, 3, 1, 3, 0, 1, 1, 2, 0, 1,
   0, 2, 0, 0, 1, 2, 0, 1, 0,
   0, 1, 0, 0};
__global__ __launch_bounds__(256) void flash_partial(
    const u16* __restrict__ Qs, const u16* __restrict__ Kb,
    const u16* __restrict__ Vt, u16* __restrict__ Opart,
    float* __restrict__ lpart)
{
  const int h    = blockIdx.x;
  const int pidx = blockIdx.y;
  const int qi = qiT[pidx];
  const int c  = cT[pidx];
  const int b  = qi >> 2;            // nchunks-1
  const int g  = h >> 2;
  const int q0 = qi << 7;
  const int nt = 2 * (qi + 1);       // key-tiles for this q-tile
  const int nc = b + 1;
  const int k0   = ((c * nt) / nc) << 6;
  const int kend = (((c + 1) * nt) / nc) << 6;

  __shared__ u16 Ks[64 * KSP];       // 17408 B
  __shared__ u16 Vs[HD * VSP];       // 18432 B
  __shared__ u16 Ps[4][32 * PSP];    // 18432 B: per-wave 32-row P (both m-tiles)

  const int tid  = threadIdx.x;
  const int lane = tid & 63;
  const int w    = tid >> 6;
  const int ln   = lane & 15;
  const int quad = lane >> 4;

  // Q A-fragments for this wave's two 16-row m-tiles
  bf16x8 aq[2][4];
#pragma unroll
  for (int mt = 0; mt < 2; ++mt) {
    const u16* qp = Qs + ((size_t)(q0 + w * 32 + mt * 16 + ln) * NH + h) * HD + quad * 8;
#pragma unroll
    for (int ks = 0; ks < 4; ++ks) aq[mt][ks] = *(const bf16x8*)&qp[ks * 32];
  }

  f32x4 o[2][8] = {};
  float rs[2][4] = {};

  const int rb0 = q0 + w * 32 + quad * 4;        // mt=0 row base (this lane)
  const int rb1 = rb0 + 16;                      // mt=1 row base
  const int rmax0 = q0 + w * 32 + 15;            // last row of m-tile 0
  const int rmax1 = q0 + w * 32 + 31;            // last row of m-tile 1

  const u16* kbase = Kb + (size_t)g * T_SEQ * HD;     // [t][d], row stride HD

  for (int jb = k0; jb < kend; jb += 64) {
    // stage K tile (64 keys x 128 d) — contiguous 16 KB stream
    {
      int r = tid >> 4, cc = (tid & 15) * 8;
#pragma unroll
      for (int i = 0; i < 4; ++i) {
        int row = i * 16 + r;
        *(bf16x8*)&Ks[row * KSP + cc] =
            *(const bf16x8*)&kbase[(size_t)(jb + row) * HD + cc];
      }
    }
    // stage V^T tile (128 d x 64 keys)
    {
      int r = tid >> 3, cc = (tid & 7) * 8;
#pragma unroll
      for (int i = 0; i < 4; ++i) {
        int row = i * 32 + r;
        *(bf16x8*)&Vs[row * VSP + cc] =
            *(const bf16x8*)&Vt[(size_t)(g * HD + row) * T_SEQ + jb + cc];
      }
    }
    __syncthreads();

    if (jb <= rmax1) {                 // wave has live rows for this tile
      const bool do0  = (jb <= rmax0);
      const bool diag = (jb >= q0);

      // ---- QK^T: each kf fragment read once, feeds both m-tiles ----
#pragma unroll
      for (int nb = 0; nb < 4; ++nb) {
        bf16x8 kf[4];
#pragma unroll
        for (int ks = 0; ks < 4; ++ks)
          kf[ks] = *(const bf16x8*)&Ks[(nb * 16 + ln) * KSP + ks * 32 + quad * 8];
        f32x4 s0 = {}, s1 = {};
#pragma unroll
        for (int ks = 0; ks < 4; ++ks) {
          if (do0) s0 = __builtin_amdgcn_mfma_f32_16x16x32_bf16(aq[0][ks], kf[ks], s0, 0, 0, 0);
          s1 = __builtin_amdgcn_mfma_f32_16x16x32_bf16(aq[1][ks], kf[ks], s1, 0, 0, 0);
        }
        const int j = jb + nb * 16 + ln;
#pragma unroll
        for (int r = 0; r < 4; ++r) {
          if (do0) {
            float p = (!diag || j <= rb0 + r) ? __expf(s0[r]) : 0.f;
            rs[0][r] += p;
            Ps[w][(quad * 4 + r) * PSP + nb * 16 + ln] = f2bf(p);
          }
          float p1 = (!diag || j <= rb1 + r) ? __expf(s1[r]) : 0.f;
          rs[1][r] += p1;
          Ps[w][(16 + quad * 4 + r) * PSP + nb * 16 + ln] = f2bf(p1);
        }
      }

      // ---- PV: each bv fragment read once, feeds both m-tiles ----
#pragma unroll
      for (int kst = 0; kst < 2; ++kst) {
        bf16x8 ap0, ap1;
        if (do0) ap0 = *(const bf16x8*)&Ps[w][ln * PSP + kst * 32 + quad * 8];
        ap1 = *(const bf16x8*)&Ps[w][(16 + ln) * PSP + kst * 32 + quad * 8];
#pragma unroll
        for (int nb8 = 0; nb8 < 8; ++nb8) {
          bf16x8 bv = *(const bf16x8*)&Vs[(nb8 * 16 + ln) * VSP + kst * 32 + quad * 8];
          if (do0) o[0][nb8] = __builtin_amdgcn_mfma_f32_16x16x32_bf16(ap0, bv, o[0][nb8], 0, 0, 0);
          o[1][nb8] = __builtin_amdgcn_mfma_f32_16x16x32_bf16(ap1, bv, o[1][nb8], 0, 0, 0);
        }
      }
    }
    __syncthreads();
  }

  // epilogue: write O partial (bf16) + row-sum partial (fp32)
  const int slot = h * 40 + 2 * b * (b + 1) + (qi & 3) * (b + 1) + c;
  u16*   op = Opart + (size_t)slot * (128 * 128);
  float* lp = lpart + (size_t)slot * 128;
#pragma unroll
  for (int mt = 0; mt < 2; ++mt) {
#pragma unroll
    for (int r = 0; r < 4; ++r)
#pragma unroll
      for (int off = 1; off < 16; off <<= 1)
        rs[mt][r] += __shfl_xor(rs[mt][r], off);
    int rowb = w * 32 + mt * 16 + quad * 4;
#pragma unroll
    for (int r = 0; r < 4; ++r) {
#pragma unroll
      for (int nb8 = 0; nb8 < 8; ++nb8)
        op[(rowb + r) * 128 + nb8 * 16 + ln] = f2bf(o[mt][nb8][r]);
      if (ln == 0) lp[rowb + r] = rs[mt][r];
    }
  }
}

// ---------------- Flash pass 2: reduce chunks + normalize ------------------
// Vectorized (G13): ushort8 per chunk per thread. block 256 = 16 t-rows x
// (16 threads x 8 d).  grid (T/16, NH).
__global__ __launch_bounds__(256) void flash_reduce(
    const u16* __restrict__ Opart, const float* __restrict__ lpart,
    u16* __restrict__ AO)
{
  const int h = blockIdx.y;
  const int tid = threadIdx.x;
  const int dgrp = tid & 15, trow = tid >> 4;
  const int t = blockIdx.x * 16 + trow;
  const int d0 = dgrp * 8;
  const int qi = t >> 7, r = t & 127;
  const int b = qi >> 2;
  const int base = h * 40 + 2 * b * (b + 1) + (qi & 3) * (b + 1);
  float so[8] = {};
  float sl = 0.f;
  for (int cc = 0; cc <= b; ++cc) {
    u16x8 ov = *(const u16x8*)&Opart[(size_t)(base + cc) * (128 * 128) + r * 128 + d0];
#pragma unroll
    for (int j = 0; j < 8; ++j) so[j] += bf2f(ov[j]);
    sl += lpart[(size_t)(base + cc) * 128 + r];
  }
  const float inv = 1.f / sl;
  u16x8 o;
#pragma unroll
  for (int j = 0; j < 8; ++j) o[j] = f2bf(so[j] * inv);
  *(u16x8*)&AO[(size_t)t * DIM + h * HD + d0] = o;
}

// ---------------- launch ----------------
// Workspace (peak 52 MB, proven safe):
//   [ 0,  8) xb bf16          (dead after QKV gemm) -> AO overlays
//   [ 8, 20) wqkvb bf16       (dead after QKV gemm) -> Qs@8, Kb@16, Vt@18
//   [20, 28) wob bf16         (live till final gemm)
//   [28, 40) P0 bf16 (QKV split-K chunk 0; dead after rope) -> Opart [28,48)
//   [40, 52) P1 bf16 (chunk 1; dead after rope)
//   [48, 48.4) lpart fp32     (written in flash, after P1 dead)
extern "C" void kernel_launch(void* const* d_in, const int* in_sizes, int n_in,
                              void* d_out, int out_size, void* d_ws, size_t ws_size,
                              hipStream_t stream) {
  const float* x    = (const float*)d_in[0];
  const float* wq   = (const float*)d_in[1];
  const float* wk   = (const float*)d_in[2];
  const float* wv   = (const float*)d_in[3];
  const float* wo   = (const float*)d_in[4];
  const float* cosT = (const float*)d_in[5];
  const float* sinT = (const float*)d_in[6];
  float* out = (float*)d_out;

  char* ws = (char*)d_ws;
  const size_t MB = 1024 * 1024;
  u16*   xb    = (u16*)(ws + 0 * MB);
  u16*   wqkvb = (u16*)(ws + 8 * MB);
  u16*   wob   = (u16*)(ws + 20 * MB);
  u16*   P0    = (u16*)(ws + 28 * MB);   // QKV split-K partials
  u16*   P1    = (u16*)(ws + 40 * MB);
  u16*   Qs    = (u16*)(ws + 8 * MB);    // overlays wqkvb (dead)
  u16*   Kb    = (u16*)(ws + 16 * MB);
  u16*   Vt    = (u16*)(ws + 18 * MB);
  u16*   AO    = (u16*)(ws + 0 * MB);    // overlays xb (dead)
  u16*   Opart = (u16*)(ws + 28 * MB);   // overlays P0/P1 (dead), 20 MB
  float* lpart = (float*)(ws + 48 * MB); // 320 KB

  // 1. all casts in one launch
  cast_all<<<B5 / 256, 256, 0, stream>>>(
      (const float4*)x, (const float4*)wq, (const float4*)wk, (const float4*)wv,
      (const float4*)wo, (ushort4*)xb, (ushort4*)wqkvb, (ushort4*)wob);

  // 2. fused QKV projection, split-K x2: partials P0/P1 (bf16)
  gemm_qkv_sk<<<dim3(NQKV / BN, T_SEQ / BM, 2), 256, 0, stream>>>(
      xb, wqkvb, P0, T_SEQ, NQKV, DIM);

  // 3. fused chunk-reduce + RoPE-Q(+scale) / RoPE-K([g][t][d]) / V-transpose
  rope_fused<<<2816, 256, 0, stream>>>(P0, P1, cosT, sinT, Qs, Kb, Vt);

  // 4a. flash attention pass 1 (balanced chunks, LPT dispatch order)
  flash_partial<<<dim3(NH, 40), 256, 0, stream>>>(Qs, Kb, Vt, Opart, lpart);
  // 4b. reduce + normalize (vectorized)
  flash_reduce<<<dim3(T_SEQ / 16, NH), 256, 0, stream>>>(Opart, lpart, AO);

  // 5. output projection, fp32 out
  gemm_bt<<<dim3(DIM / BN, T_SEQ / BM), 256, 0, stream>>>(
      AO, wob, out, nullptr, T_SEQ, DIM, DIM);
}